// Round 5
// baseline (365.285 us; speedup 1.0000x reference)
//
#include <hip/hip_runtime.h>
#include <stdint.h>
#include <math.h>

#define DEV static __device__ __forceinline__

typedef __attribute__((ext_vector_type(8))) __bf16 bf16x8;
typedef __attribute__((ext_vector_type(4))) float f32x4;
typedef unsigned short u16;

// fp32 -> bf16, round-to-nearest-even
DEV u16 f2b(float f) {
  union { float f; uint32_t u; } x; x.f = f;
  uint32_t r = x.u + 0x7fffu + ((x.u >> 16) & 1u);
  return (u16)(r >> 16);
}

DEV uint32_t pk2(float a, float b) {
  return (uint32_t)f2b(a) | ((uint32_t)f2b(b) << 16);
}

DEV float b2f_lo(uint32_t u) { return __uint_as_float(u << 16); }
DEV float b2f_hi(uint32_t u) { return __uint_as_float(u & 0xffff0000u); }

DEV void glds16(const void* g, void* l) {
  __builtin_amdgcn_global_load_lds(
      (const __attribute__((address_space(1))) void*)g,
      (__attribute__((address_space(3))) void*)l, 16, 0, 0);
}

DEV f32x4 mfma16(bf16x8 a, bf16x8 b, f32x4 c) {
  return __builtin_amdgcn_mfma_f32_16x16x32_bf16(a, b, c, 0, 0, 0);
}

// ---------------- single fused fp32 -> bf16 conversion ----------------
// Segments (element offsets, all boundaries multiples of 1024 = one block):
// x[0,8M) Wq[8M,9M) Wk[9M,10M) Wv[10M,11M) Wo[11M,12M) bias[12M,16M)
__global__ __launch_bounds__(256) void cvt_all(
    const float* __restrict__ x, const float* __restrict__ Wq,
    const float* __restrict__ Wk, const float* __restrict__ Wv,
    const float* __restrict__ Wo, const float* __restrict__ bias,
    u16* __restrict__ xb, u16* __restrict__ wqkv, u16* __restrict__ wo,
    u16* __restrict__ biasb) {
  size_t i = ((size_t)blockIdx.x * 256 + threadIdx.x) * 4;
  const float* s;
  u16* d;
  size_t off;
  float scale = 1.0f;
  if (i < 8388608)        { s = x;  d = xb;             off = i; }
  else if (i < 9437184)   { s = Wq; d = wqkv;           off = i - 8388608; }
  else if (i < 10485760)  { s = Wk; d = wqkv + 1048576; off = i - 9437184; }
  else if (i < 11534336)  { s = Wv; d = wqkv + 2097152; off = i - 10485760; }
  else if (i < 12582912)  { s = Wo; d = wo;             off = i - 11534336; }
  else { s = bias; d = biasb; off = i - 12582912; scale = 1.44269504f; }
  float4 v = *(const float4*)(s + off);
  ushort4 o;
  o.x = f2b(v.x * scale); o.y = f2b(v.y * scale);
  o.z = f2b(v.z * scale); o.w = f2b(v.w * scale);
  *(ushort4*)(d + off) = o;
}

// ---------------- fused QKV projection GEMM ----------------
// A: (8192,1024) bf16 row-major (x). Bw: (3072,1024) bf16 = [Wq;Wk;Wv] rows.
// Q,K -> (BH, T, 72) padded;  V -> (BH, 4, 64, 136) pre-tiled V^T.
// Grid = 768 blocks (exactly 3/CU, single residency round, no tail).
// Each block: one n0 strip, TWO consecutive m-tiles (B strip L2-warm for t=1).
__global__ __launch_bounds__(256) void gemm_qkv(
    const u16* __restrict__ A, const u16* __restrict__ Bw,
    const float* __restrict__ bq, const float* __restrict__ bk,
    const float* __restrict__ bv,
    u16* __restrict__ qo, u16* __restrict__ ko, u16* __restrict__ vto) {
  __shared__ u16 lsA[2][128 * 32];
  __shared__ u16 lsB[2][128 * 32];
  const int K = 1024;
  int tid = threadIdx.x, wave = tid >> 6, lane = tid & 63;
  int q16 = lane >> 4, c16 = lane & 15;
  int p = blockIdx.x;
  int n0 = (p % 24) * 128;
  int mpair = p / 24;
  int wm = wave >> 1, wn = wave & 1;
  const bool vblk = (n0 >= 2048);
  // role swap: rows of D come from lsR (wr), cols from lsC (wc)
  const u16* lsR = vblk ? &lsB[0][0] : &lsA[0][0];
  const u16* lsC = vblk ? &lsA[0][0] : &lsB[0][0];
  int wr = vblk ? wn : wm;
  int wc = vblk ? wm : wn;

  int srow = (lane >> 2);
  int scol = (lane & 3) * 8;

  for (int t = 0; t < 2; ++t) {
    int m0 = mpair * 256 + t * 128;

    f32x4 acc[4][4];
#pragma unroll
    for (int i = 0; i < 4; ++i)
#pragma unroll
      for (int j = 0; j < 4; ++j) acc[i][j] = (f32x4)0.0f;

    for (int k0 = 0; k0 < K; k0 += 64) {
      __syncthreads();
#pragma unroll
      for (int half = 0; half < 2; ++half) {
#pragma unroll
        for (int cc = 0; cc < 2; ++cc) {
          int chunk = wave * 2 + cc;
          int r = chunk * 16 + srow;
          glds16(A + (size_t)(m0 + r) * K + k0 + half * 32 + scol,
                 &lsA[half][chunk * 512]);
          glds16(Bw + (size_t)(n0 + r) * K + k0 + half * 32 + scol,
                 &lsB[half][chunk * 512]);
        }
      }
      __syncthreads();
#pragma unroll
      for (int half = 0; half < 2; ++half) {
        bf16x8 rf[4], cf[4];
#pragma unroll
        for (int i = 0; i < 4; ++i)
          rf[i] = *(const bf16x8*)&lsR[half * 4096 +
                                       (wr * 64 + i * 16 + c16) * 32 + q16 * 8];
#pragma unroll
        for (int i = 0; i < 4; ++i)
          cf[i] = *(const bf16x8*)&lsC[half * 4096 +
                                       (wc * 64 + i * 16 + c16) * 32 + q16 * 8];
#pragma unroll
        for (int it = 0; it < 4; ++it)
#pragma unroll
          for (int jt = 0; jt < 4; ++jt)
            acc[it][jt] = mfma16(rf[it], cf[jt], acc[it][jt]);
      }
    }

    if (!vblk) {
      // rows = m (t), cols = n (head dim)
#pragma unroll
      for (int mt = 0; mt < 4; ++mt) {
#pragma unroll
        for (int nt = 0; nt < 4; ++nt) {
          int n = n0 + wn * 64 + nt * 16 + c16;
          int which = n >> 10;
          int nl = n & 1023;
          int hh = nl >> 6, d = nl & 63;
          float bias = (which == 0 ? bq : bk)[nl];
          u16* dst = (which == 0 ? qo : ko);
#pragma unroll
          for (int r = 0; r < 4; ++r) {
            int m = m0 + wm * 64 + mt * 16 + q16 * 4 + r;
            int b = m >> 9, tt = m & 511;
            size_t bh = (size_t)b * 16 + hh;
            dst[(bh * 512 + tt) * 72 + d] = f2b(acc[mt][nt][r] + bias);
          }
        }
      }
    } else {
      // rows = n (head dim d), cols = m (t): D^T, coalesced over t
#pragma unroll
      for (int it = 0; it < 4; ++it) {
        int nbase = n0 + wn * 64 + it * 16 + q16 * 4;  // wr == wn
        float4 bvv = *(const float4*)(bv + (nbase & 1023));
#pragma unroll
        for (int jt = 0; jt < 4; ++jt) {
          int m = m0 + wm * 64 + jt * 16 + c16;  // wc == wm
          int b = m >> 9, tt = m & 511;
          size_t bh4 = ((size_t)b * 16) * 4;
#pragma unroll
          for (int r = 0; r < 4; ++r) {
            int nl = (nbase + r) & 1023;
            int hh = nl >> 6, d = nl & 63;
            float bias = ((const float*)&bvv)[r];
            vto[((bh4 + (size_t)hh * 4 + (tt >> 7)) * 64 + d) * 136 +
                (tt & 127)] = f2b(acc[it][jt][r] + bias);
          }
        }
      }
    }
  }
}

// ---------------- flash attention (S^T orientation) ----------------
// One q-tile pass. Shapes: q,k (BH,512,72); vt (BH,4,64,136); biasb (H,512,512)
// bf16 pre-scaled by log2(e); out (B,T,C) bf16.
DEV void attn_tile(int bx, int bh, const u16* __restrict__ qglob,
                   const u16* __restrict__ kglob,
                   const u16* __restrict__ vtglob,
                   const u16* __restrict__ biasb, u16* __restrict__ og,
                   u16* lsK, u16* lsV, u16* lsP, int wave, int lane) {
  int q16 = lane >> 4, c16 = lane & 15;
  int b = bh >> 4, h = bh & 15;
  int q0 = bx * 128;

  const u16* qbase = qglob + (size_t)bh * (512 * 72) + (size_t)q0 * 72;
  const u16* kbase = kglob + (size_t)bh * (512 * 72);
  const u16* vbase = vtglob + (size_t)bh * 4 * (64 * 136);
  u16* lsPw = lsP + wave * (32 * 72);

  // stage Q tile (contiguous 128x72 u16) into lsK
  for (int i = wave; i < 18; i += 4)
    glds16(qbase + (size_t)i * 512 + lane * 8, lsK + i * 512);
  __syncthreads();
  bf16x8 qf[2][2];
#pragma unroll
  for (int nt = 0; nt < 2; ++nt)
#pragma unroll
    for (int ks = 0; ks < 2; ++ks)
      qf[nt][ks] = *(const bf16x8*)&lsK[(wave * 32 + nt * 16 + c16) * 72 +
                                        ks * 32 + q16 * 8];

  f32x4 oacc[2][4];
#pragma unroll
  for (int i = 0; i < 2; ++i)
#pragma unroll
    for (int j = 0; j < 4; ++j) oacc[i][j] = (f32x4)0.0f;
  float mold[2] = {-INFINITY, -INFINITY};
  float lsum[2] = {0.0f, 0.0f};
  const float SCL = 0.18033688f;  // (1/sqrt(64)) * log2(e)

  for (int st = 0; st <= bx; ++st) {
    bool diag = (st == bx);
    __syncthreads();  // prior iter done with lsK/lsV/lsP
    const u16* kt = kbase + (size_t)st * (128 * 72);
    for (int i = wave; i < 18; i += 4)
      glds16(kt + (size_t)i * 512 + lane * 8, lsK + i * 512);
    const u16* vt = vbase + (size_t)st * (64 * 136);
    for (int i = wave; i < 17; i += 4)
      glds16(vt + (size_t)i * 512 + lane * 8, lsV + i * 512);

    // prefetch bias rows (bf16, pre-scaled); completes during staging drain
    uint2 ub[2][8];
#pragma unroll
    for (int nt = 0; nt < 2; ++nt) {
      int qgl = q0 + wave * 32 + nt * 16 + c16;
      const u16* bp = biasb + ((size_t)h * 512 + qgl) * 512 + st * 128 + q16 * 4;
#pragma unroll
      for (int mt = 0; mt < 8; ++mt) ub[nt][mt] = *(const uint2*)(bp + mt * 16);
    }
    __syncthreads();  // drains vmcnt (staging + bias prefetch)

    // S^T = K Q^T : rows s (8 m-tiles), cols q (2 n-tiles = wave's 32 rows)
    f32x4 sa[8][2];
#pragma unroll
    for (int mt = 0; mt < 8; ++mt) {
      sa[mt][0] = (f32x4)0.0f;
      sa[mt][1] = (f32x4)0.0f;
    }
    int mtmax = diag ? 2 * wave + 2 : 8;
#pragma unroll
    for (int mt = 0; mt < 8; ++mt) {
      if (mt < mtmax) {
#pragma unroll
        for (int ks = 0; ks < 2; ++ks) {
          bf16x8 kf =
              *(const bf16x8*)&lsK[(mt * 16 + c16) * 72 + ks * 32 + q16 * 8];
          sa[mt][0] = mfma16(kf, qf[0][ks], sa[mt][0]);
          sa[mt][1] = mfma16(kf, qf[1][ks], sa[mt][1]);
        }
      }
    }

    // online softmax: reduce over s = (mt, r) in-register + 2 shuffles
    float alpha[2];
#pragma unroll
    for (int nt = 0; nt < 2; ++nt) {
#pragma unroll
      for (int mt = 0; mt < 8; ++mt) {
        uint32_t lo = ub[nt][mt].x, hi = ub[nt][mt].y;
        f32x4 bv;
        bv[0] = b2f_lo(lo); bv[1] = b2f_hi(lo);
        bv[2] = b2f_lo(hi); bv[3] = b2f_hi(hi);
        sa[mt][nt] = sa[mt][nt] * SCL + bv;
      }
      if (diag) {
        // mask s > q  (s0 == q0 on diagonal tile)
#pragma unroll
        for (int mt = 0; mt < 8; ++mt) {
          int d0 = mt * 16 + q16 * 4 - wave * 32 - nt * 16 - c16;
#pragma unroll
          for (int r = 0; r < 4; ++r)
            if (d0 + r > 0) sa[mt][nt][r] = -INFINITY;
        }
      }
      f32x4 m4 = sa[0][nt];
#pragma unroll
      for (int mt = 1; mt < 8; ++mt) {
        f32x4 v = sa[mt][nt];
        m4[0] = fmaxf(m4[0], v[0]); m4[1] = fmaxf(m4[1], v[1]);
        m4[2] = fmaxf(m4[2], v[2]); m4[3] = fmaxf(m4[3], v[3]);
      }
      float mx = fmaxf(fmaxf(m4[0], m4[1]), fmaxf(m4[2], m4[3]));
      mx = fmaxf(mx, __shfl_xor(mx, 16));
      mx = fmaxf(mx, __shfl_xor(mx, 32));
      float mnew = fmaxf(mold[nt], mx);
      alpha[nt] = exp2f(mold[nt] - mnew);
      mold[nt] = mnew;
      f32x4 s4 = (f32x4)0.0f;
#pragma unroll
      for (int mt = 0; mt < 8; ++mt) {
        f32x4 p;
        p[0] = exp2f(sa[mt][nt][0] - mnew);
        p[1] = exp2f(sa[mt][nt][1] - mnew);
        p[2] = exp2f(sa[mt][nt][2] - mnew);
        p[3] = exp2f(sa[mt][nt][3] - mnew);
        sa[mt][nt] = p;
        s4 += p;
      }
      float ss = (s4[0] + s4[1]) + (s4[2] + s4[3]);
      ss += __shfl_xor(ss, 16);
      ss += __shfl_xor(ss, 32);
      lsum[nt] = lsum[nt] * alpha[nt] + ss;
    }

    // rescale O by alpha (broadcast col-state -> row-state via shfl)
#pragma unroll
    for (int mo = 0; mo < 2; ++mo) {
      f32x4 av;
#pragma unroll
      for (int r = 0; r < 4; ++r) av[r] = __shfl(alpha[mo], q16 * 4 + r);
#pragma unroll
      for (int dt = 0; dt < 4; ++dt) oacc[mo][dt] *= av;
    }

    // O += P V, in two s-halves through per-wave LDS (C-layout -> A-layout)
    int G = diag ? wave + 1 : 4;  // valid 32-wide s-groups
#pragma unroll
    for (int hf = 0; hf < 2; ++hf) {
      if (hf * 2 < G) {
#pragma unroll
        for (int nt = 0; nt < 2; ++nt)
#pragma unroll
          for (int mt4 = 0; mt4 < 4; ++mt4) {
            f32x4 p = sa[hf * 4 + mt4][nt];
            uint2 w;
            w.x = pk2(p[0], p[1]);
            w.y = pk2(p[2], p[3]);
            *(uint2*)&lsPw[(nt * 16 + c16) * 72 + mt4 * 16 + q16 * 4] = w;
          }
#pragma unroll
        for (int ksh = 0; ksh < 2; ++ksh) {
          if (hf * 2 + ksh < G) {
            bf16x8 pf0 =
                *(const bf16x8*)&lsPw[c16 * 72 + ksh * 32 + q16 * 8];
            bf16x8 pf1 =
                *(const bf16x8*)&lsPw[(16 + c16) * 72 + ksh * 32 + q16 * 8];
#pragma unroll
            for (int dt = 0; dt < 4; ++dt) {
              bf16x8 vf = *(const bf16x8*)&lsV[(dt * 16 + c16) * 136 +
                                               hf * 64 + ksh * 32 + q16 * 8];
              oacc[0][dt] = mfma16(pf0, vf, oacc[0][dt]);
              oacc[1][dt] = mfma16(pf1, vf, oacc[1][dt]);
            }
          }
        }
      }
    }
  }

  // epilogue: O /= l, write (B,T,C) bf16
#pragma unroll
  for (int mo = 0; mo < 2; ++mo) {
    f32x4 lv;
#pragma unroll
    for (int r = 0; r < 4; ++r) lv[r] = __shfl(lsum[mo], q16 * 4 + r);
#pragma unroll
    for (int r = 0; r < 4; ++r) {
      int tg = q0 + wave * 32 + mo * 16 + q16 * 4 + r;
      float inv = 1.0f / lv[r];
#pragma unroll
      for (int dt = 0; dt < 4; ++dt)
        og[((size_t)b * 512 + tg) * 1024 + h * 64 + dt * 16 + c16] =
            f2b(oacc[mo][dt][r] * inv);
    }
  }
}

// 3 roles per bh: role0 -> bx=3 (4 iters), role1 -> bx=2,0 (4), role2 -> bx=1
// (2). 768 blocks = exactly 3/CU resident in a single round.
__global__ __launch_bounds__(256, 3) void attn_kernel(
    const u16* __restrict__ qglob, const u16* __restrict__ kglob,
    const u16* __restrict__ vtglob, const u16* __restrict__ biasb,
    u16* __restrict__ og) {
  __shared__ u16 lsK[128 * 72];
  __shared__ u16 lsV[64 * 136];
  __shared__ u16 lsP[4 * 32 * 72];
  int tid = threadIdx.x, wave = tid >> 6, lane = tid & 63;
  int role = blockIdx.x, bh = blockIdx.y;
  if (role == 0) {
    attn_tile(3, bh, qglob, kglob, vtglob, biasb, og, lsK, lsV, lsP, wave, lane);
  } else if (role == 1) {
    attn_tile(2, bh, qglob, kglob, vtglob, biasb, og, lsK, lsV, lsP, wave, lane);
    __syncthreads();
    attn_tile(0, bh, qglob, kglob, vtglob, biasb, og, lsK, lsV, lsP, wave, lane);
  } else {
    attn_tile(1, bh, qglob, kglob, vtglob, biasb, og, lsK, lsV, lsP, wave, lane);
  }
}

// ---------------- output projection GEMM ----------------
// BK=64 dual-buffer K-loop; grid 512 = exactly 2/CU (balanced).
__global__ __launch_bounds__(256) void gemm_out(
    const u16* __restrict__ A, const u16* __restrict__ W,
    const float* __restrict__ bo, float* __restrict__ out) {
  __shared__ u16 lsA[2][128 * 32];
  __shared__ u16 lsB[2][128 * 32];
  const int K = 1024;
  int tid = threadIdx.x, wave = tid >> 6, lane = tid & 63;
  int q16 = lane >> 4, c16 = lane & 15;
  int m0 = blockIdx.y * 128, n0 = blockIdx.x * 128;
  int wm = wave >> 1, wn = wave & 1;

  f32x4 acc[4][4];
#pragma unroll
  for (int i = 0; i < 4; ++i)
#pragma unroll
    for (int j = 0; j < 4; ++j) acc[i][j] = (f32x4)0.0f;

  int srow = (lane >> 2);
  int scol = (lane & 3) * 8;

  for (int k0 = 0; k0 < K; k0 += 64) {
    __syncthreads();
#pragma unroll
    for (int half = 0; half < 2; ++half) {
#pragma unroll
      for (int cc = 0; cc < 2; ++cc) {
        int chunk = wave * 2 + cc;
        int r = chunk * 16 + srow;
        glds16(A + (size_t)(m0 + r) * K + k0 + half * 32 + scol,
               &lsA[half][chunk * 512]);
        glds16(W + (size_t)(n0 + r) * K + k0 + half * 32 + scol,
               &lsB[half][chunk * 512]);
      }
    }
    __syncthreads();
#pragma unroll
    for (int half = 0; half < 2; ++half) {
      bf16x8 af[4], bf[4];
#pragma unroll
      for (int i = 0; i < 4; ++i)
        af[i] = *(const bf16x8*)&lsA[half][(wm * 64 + i * 16 + c16) * 32 + q16 * 8];
#pragma unroll
      for (int i = 0; i < 4; ++i)
        bf[i] = *(const bf16x8*)&lsB[half][(wn * 64 + i * 16 + c16) * 32 + q16 * 8];
#pragma unroll
      for (int mt = 0; mt < 4; ++mt)
#pragma unroll
        for (int nt = 0; nt < 4; ++nt)
          acc[mt][nt] = mfma16(af[mt], bf[nt], acc[mt][nt]);
    }
  }

#pragma unroll
  for (int mt = 0; mt < 4; ++mt) {
#pragma unroll
    for (int nt = 0; nt < 4; ++nt) {
      int n = n0 + wn * 64 + nt * 16 + c16;
      float bias = bo[n];
#pragma unroll
      for (int r = 0; r < 4; ++r) {
        int m = m0 + wm * 64 + mt * 16 + q16 * 4 + r;
        out[(size_t)m * 1024 + n] = acc[mt][nt][r] + bias;
      }
    }
  }
}

extern "C" void kernel_launch(void* const* d_in, const int* in_sizes, int n_in,
                              void* d_out, int out_size, void* d_ws, size_t ws_size,
                              hipStream_t stream) {
  const float* x    = (const float*)d_in[0];
  const float* Wq   = (const float*)d_in[1];
  const float* bq   = (const float*)d_in[2];
  const float* Wk   = (const float*)d_in[3];
  const float* bk   = (const float*)d_in[4];
  const float* Wv   = (const float*)d_in[5];
  const float* bv   = (const float*)d_in[6];
  const float* Wo   = (const float*)d_in[7];
  const float* bo   = (const float*)d_in[8];
  const float* bias = (const float*)d_in[9];
  float* out = (float*)d_out;

  const size_t MB = 1u << 20;
  char* ws = (char*)d_ws;
  u16* xb    = (u16*)(ws);              // 16 MiB: x bf16 / reused as attn out
  u16* wqkv  = (u16*)(ws + 16 * MB);    // 6 MiB
  u16* wo    = (u16*)(ws + 22 * MB);    // 2 MiB
  u16* biasb = (u16*)(ws + 24 * MB);    // 8 MiB (bf16, pre-scaled by log2e)
  u16* qb    = (u16*)(ws + 32 * MB);    // 18 MiB (BH,512,72)
  u16* kb    = (u16*)(ws + 50 * MB);    // 18 MiB (BH,512,72)
  u16* vtb   = (u16*)(ws + 68 * MB);    // 17 MiB (BH,4,64,136)
  u16* ab    = xb;                      // attn output overlays xb

  cvt_all<<<16384, 256, 0, stream>>>(x, Wq, Wk, Wv, Wo, bias,
                                     xb, wqkv, wo, biasb);
  gemm_qkv<<<768, 256, 0, stream>>>(xb, wqkv, bq, bk, bv, qb, kb, vtb);
  attn_kernel<<<dim3(3, 256), 256, 0, stream>>>(qb, kb, vtb, biasb, ab);
  gemm_out<<<dim3(8, 64), 256, 0, stream>>>(ab, wo, bo, out);
}

// Round 6
// 289.654 us; speedup vs baseline: 1.2611x; 1.2611x over previous
//
#include <hip/hip_runtime.h>
#include <stdint.h>
#include <math.h>

#define DEV static __device__ __forceinline__

typedef __attribute__((ext_vector_type(8))) __bf16 bf16x8;
typedef __attribute__((ext_vector_type(4))) float f32x4;
typedef unsigned short u16;

// fp32 -> bf16, round-to-nearest-even
DEV u16 f2b(float f) {
  union { float f; uint32_t u; } x; x.f = f;
  uint32_t r = x.u + 0x7fffu + ((x.u >> 16) & 1u);
  return (u16)(r >> 16);
}

DEV uint32_t pk2(float a, float b) {
  return (uint32_t)f2b(a) | ((uint32_t)f2b(b) << 16);
}

DEV float b2f_lo(uint32_t u) { return __uint_as_float(u << 16); }
DEV float b2f_hi(uint32_t u) { return __uint_as_float(u & 0xffff0000u); }

DEV void glds16(const void* g, void* l) {
  __builtin_amdgcn_global_load_lds(
      (const __attribute__((address_space(1))) void*)g,
      (__attribute__((address_space(3))) void*)l, 16, 0, 0);
}

DEV f32x4 mfma16(bf16x8 a, bf16x8 b, f32x4 c) {
  return __builtin_amdgcn_mfma_f32_16x16x32_bf16(a, b, c, 0, 0, 0);
}

// ---------------- single fused fp32 -> bf16 conversion ----------------
// Segments (element offsets, all boundaries multiples of 1024 = one block):
// x[0,8M) Wq[8M,9M) Wk[9M,10M) Wv[10M,11M) Wo[11M,12M) bias[12M,16M)
__global__ __launch_bounds__(256) void cvt_all(
    const float* __restrict__ x, const float* __restrict__ Wq,
    const float* __restrict__ Wk, const float* __restrict__ Wv,
    const float* __restrict__ Wo, const float* __restrict__ bias,
    u16* __restrict__ xb, u16* __restrict__ wqkv, u16* __restrict__ wo,
    u16* __restrict__ biasb) {
  size_t i = ((size_t)blockIdx.x * 256 + threadIdx.x) * 4;
  const float* s;
  u16* d;
  size_t off;
  float scale = 1.0f;
  if (i < 8388608)        { s = x;  d = xb;             off = i; }
  else if (i < 9437184)   { s = Wq; d = wqkv;           off = i - 8388608; }
  else if (i < 10485760)  { s = Wk; d = wqkv + 1048576; off = i - 9437184; }
  else if (i < 11534336)  { s = Wv; d = wqkv + 2097152; off = i - 10485760; }
  else if (i < 12582912)  { s = Wo; d = wo;             off = i - 11534336; }
  else { s = bias; d = biasb; off = i - 12582912; scale = 1.44269504f; }
  float4 v = *(const float4*)(s + off);
  ushort4 o;
  o.x = f2b(v.x * scale); o.y = f2b(v.y * scale);
  o.z = f2b(v.z * scale); o.w = f2b(v.w * scale);
  *(ushort4*)(d + off) = o;
}

// ---------------- fused QKV projection GEMM ----------------
// A: (8192,1024) bf16 row-major (x). Bw: (3072,1024) bf16 = [Wq;Wk;Wv] rows.
// Q,K -> (BH, T, 72) padded;  V -> (BH, 4, 64, 136) pre-tiled V^T.
// BK=64 dual 32-k buffers under one barrier pair. LDS k-colgroup XOR-swizzle:
// staged colgroup = (lane&3)^((lane>>3)&3); read colgroup = q16^((c16>>1)&3).
// Turns the 4-way ds_read_b128 bank conflict into free 2-way aliasing.
__global__ __launch_bounds__(256) void gemm_qkv(
    const u16* __restrict__ A, const u16* __restrict__ Bw,
    const float* __restrict__ bq, const float* __restrict__ bk,
    const float* __restrict__ bv,
    u16* __restrict__ qo, u16* __restrict__ ko, u16* __restrict__ vto) {
  __shared__ u16 lsA[2][128 * 32];
  __shared__ u16 lsB[2][128 * 32];
  const int K = 1024;
  int tid = threadIdx.x, wave = tid >> 6, lane = tid & 63;
  int q16 = lane >> 4, c16 = lane & 15;
  int m0 = blockIdx.y * 128, n0 = blockIdx.x * 128;
  int wm = wave >> 1, wn = wave & 1;
  const bool vblk = (n0 >= 2048);
  // role swap: rows of D come from lsR (wr), cols from lsC (wc)
  const u16* lsR = vblk ? &lsB[0][0] : &lsA[0][0];
  const u16* lsC = vblk ? &lsA[0][0] : &lsB[0][0];
  int wr = vblk ? wn : wm;
  int wc = vblk ? wm : wn;

  f32x4 acc[4][4];
#pragma unroll
  for (int i = 0; i < 4; ++i)
#pragma unroll
    for (int j = 0; j < 4; ++j) acc[i][j] = (f32x4)0.0f;

  int srow = (lane >> 2);
  int scol = ((lane & 3) ^ ((lane >> 3) & 3)) * 8;  // XOR-swizzled colgroup
  int swz = (q16 ^ ((c16 >> 1) & 3)) * 8;           // read-side colgroup

  for (int k0 = 0; k0 < K; k0 += 64) {
    __syncthreads();
#pragma unroll
    for (int half = 0; half < 2; ++half) {
#pragma unroll
      for (int cc = 0; cc < 2; ++cc) {
        int chunk = wave * 2 + cc;
        int r = chunk * 16 + srow;
        glds16(A + (size_t)(m0 + r) * K + k0 + half * 32 + scol,
               &lsA[half][chunk * 512]);
        glds16(Bw + (size_t)(n0 + r) * K + k0 + half * 32 + scol,
               &lsB[half][chunk * 512]);
      }
    }
    __syncthreads();
#pragma unroll
    for (int half = 0; half < 2; ++half) {
      bf16x8 rf[4], cf[4];
#pragma unroll
      for (int i = 0; i < 4; ++i)
        rf[i] = *(const bf16x8*)&lsR[half * 4096 +
                                     (wr * 64 + i * 16 + c16) * 32 + swz];
#pragma unroll
      for (int i = 0; i < 4; ++i)
        cf[i] = *(const bf16x8*)&lsC[half * 4096 +
                                     (wc * 64 + i * 16 + c16) * 32 + swz];
#pragma unroll
      for (int it = 0; it < 4; ++it)
#pragma unroll
        for (int jt = 0; jt < 4; ++jt)
          acc[it][jt] = mfma16(rf[it], cf[jt], acc[it][jt]);
    }
  }

  if (!vblk) {
    // rows = m (t), cols = n (head dim)
#pragma unroll
    for (int mt = 0; mt < 4; ++mt) {
#pragma unroll
      for (int nt = 0; nt < 4; ++nt) {
        int n = n0 + wn * 64 + nt * 16 + c16;
        int which = n >> 10;
        int nl = n & 1023;
        int hh = nl >> 6, d = nl & 63;
        float bias = (which == 0 ? bq : bk)[nl];
        u16* dst = (which == 0 ? qo : ko);
#pragma unroll
        for (int r = 0; r < 4; ++r) {
          int m = m0 + wm * 64 + mt * 16 + q16 * 4 + r;
          int b = m >> 9, t = m & 511;
          size_t bh = (size_t)b * 16 + hh;
          dst[(bh * 512 + t) * 72 + d] = f2b(acc[mt][nt][r] + bias);
        }
      }
    }
  } else {
    // rows = n (head dim d), cols = m (t): D^T, coalesced over t
#pragma unroll
    for (int it = 0; it < 4; ++it) {
      int nbase = n0 + wn * 64 + it * 16 + q16 * 4;  // wr == wn
      float4 bvv = *(const float4*)(bv + (nbase & 1023));
#pragma unroll
      for (int jt = 0; jt < 4; ++jt) {
        int m = m0 + wm * 64 + jt * 16 + c16;  // wc == wm
        int b = m >> 9, t = m & 511;
        size_t bh4 = ((size_t)b * 16) * 4;
#pragma unroll
        for (int r = 0; r < 4; ++r) {
          int nl = (nbase + r) & 1023;
          int hh = nl >> 6, d = nl & 63;
          float bias = ((const float*)&bvv)[r];
          vto[((bh4 + (size_t)hh * 4 + (t >> 7)) * 64 + d) * 136 + (t & 127)] =
              f2b(acc[it][jt][r] + bias);
        }
      }
    }
  }
}

// ---------------- flash attention (S^T orientation) ----------------
// q,k: (BH, 512, 72) bf16 padded; vt: (BH, 4, 64, 136) bf16 pre-tiled V^T
// biasb: (H,512,512) bf16, pre-scaled by log2(e). out: (B,T,C) bf16.
__global__ __launch_bounds__(256, 3) void attn_kernel(
    const u16* __restrict__ qglob, const u16* __restrict__ kglob,
    const u16* __restrict__ vtglob, const u16* __restrict__ biasb,
    u16* __restrict__ og) {
  __shared__ u16 lsK[128 * 72];      // K tile (s,d) padded; also Q staging
  __shared__ u16 lsV[64 * 136];      // V^T tile (d,s) padded
  __shared__ u16 lsP[4 * 32 * 72];   // per-wave P half-tile (q, s-half) padded

  int tid = threadIdx.x, wave = tid >> 6, lane = tid & 63;
  int q16 = lane >> 4, c16 = lane & 15;
  int bh = blockIdx.y;
  int b = bh >> 4, h = bh & 15;
  int bx = blockIdx.x;
  int q0 = bx * 128;

  const u16* qbase = qglob + (size_t)bh * (512 * 72) + (size_t)q0 * 72;
  const u16* kbase = kglob + (size_t)bh * (512 * 72);
  const u16* vbase = vtglob + (size_t)bh * 4 * (64 * 136);
  u16* lsPw = lsP + wave * (32 * 72);

  // stage Q tile (contiguous 128x72 u16) into lsK
  for (int i = wave; i < 18; i += 4)
    glds16(qbase + (size_t)i * 512 + lane * 8, lsK + i * 512);
  __syncthreads();
  bf16x8 qf[2][2];
#pragma unroll
  for (int nt = 0; nt < 2; ++nt)
#pragma unroll
    for (int ks = 0; ks < 2; ++ks)
      qf[nt][ks] = *(const bf16x8*)&lsK[(wave * 32 + nt * 16 + c16) * 72 +
                                        ks * 32 + q16 * 8];

  f32x4 oacc[2][4];
#pragma unroll
  for (int i = 0; i < 2; ++i)
#pragma unroll
    for (int j = 0; j < 4; ++j) oacc[i][j] = (f32x4)0.0f;
  float mold[2] = {-INFINITY, -INFINITY};
  float lsum[2] = {0.0f, 0.0f};
  const float SCL = 0.18033688f;  // (1/sqrt(64)) * log2(e)

  for (int st = 0; st <= bx; ++st) {
    bool diag = (st == bx);
    __syncthreads();  // prior iter done with lsK/lsV/lsP
    const u16* kt = kbase + (size_t)st * (128 * 72);
    for (int i = wave; i < 18; i += 4)
      glds16(kt + (size_t)i * 512 + lane * 8, lsK + i * 512);
    const u16* vt = vbase + (size_t)st * (64 * 136);
    for (int i = wave; i < 17; i += 4)
      glds16(vt + (size_t)i * 512 + lane * 8, lsV + i * 512);

    // prefetch bias rows (bf16, pre-scaled); completes during staging drain
    uint2 ub[2][8];
#pragma unroll
    for (int nt = 0; nt < 2; ++nt) {
      int qgl = q0 + wave * 32 + nt * 16 + c16;
      const u16* bp = biasb + ((size_t)h * 512 + qgl) * 512 + st * 128 + q16 * 4;
#pragma unroll
      for (int mt = 0; mt < 8; ++mt) ub[nt][mt] = *(const uint2*)(bp + mt * 16);
    }
    __syncthreads();  // drains vmcnt (staging + bias prefetch)

    // S^T = K Q^T : rows s (8 m-tiles), cols q (2 n-tiles = wave's 32 rows)
    f32x4 sa[8][2];
#pragma unroll
    for (int mt = 0; mt < 8; ++mt) {
      sa[mt][0] = (f32x4)0.0f;
      sa[mt][1] = (f32x4)0.0f;
    }
    int mtmax = diag ? 2 * wave + 2 : 8;
#pragma unroll
    for (int mt = 0; mt < 8; ++mt) {
      if (mt < mtmax) {
#pragma unroll
        for (int ks = 0; ks < 2; ++ks) {
          bf16x8 kf =
              *(const bf16x8*)&lsK[(mt * 16 + c16) * 72 + ks * 32 + q16 * 8];
          sa[mt][0] = mfma16(kf, qf[0][ks], sa[mt][0]);
          sa[mt][1] = mfma16(kf, qf[1][ks], sa[mt][1]);
        }
      }
    }

    // online softmax: reduce over s = (mt, r) in-register + 2 shuffles
    float alpha[2];
#pragma unroll
    for (int nt = 0; nt < 2; ++nt) {
#pragma unroll
      for (int mt = 0; mt < 8; ++mt) {
        uint32_t lo = ub[nt][mt].x, hi = ub[nt][mt].y;
        f32x4 bv;
        bv[0] = b2f_lo(lo); bv[1] = b2f_hi(lo);
        bv[2] = b2f_lo(hi); bv[3] = b2f_hi(hi);
        sa[mt][nt] = sa[mt][nt] * SCL + bv;
      }
      if (diag) {
        // mask s > q  (s0 == q0 on diagonal tile)
#pragma unroll
        for (int mt = 0; mt < 8; ++mt) {
          int d0 = mt * 16 + q16 * 4 - wave * 32 - nt * 16 - c16;
#pragma unroll
          for (int r = 0; r < 4; ++r)
            if (d0 + r > 0) sa[mt][nt][r] = -INFINITY;
        }
      }
      f32x4 m4 = sa[0][nt];
#pragma unroll
      for (int mt = 1; mt < 8; ++mt) {
        f32x4 v = sa[mt][nt];
        m4[0] = fmaxf(m4[0], v[0]); m4[1] = fmaxf(m4[1], v[1]);
        m4[2] = fmaxf(m4[2], v[2]); m4[3] = fmaxf(m4[3], v[3]);
      }
      float mx = fmaxf(fmaxf(m4[0], m4[1]), fmaxf(m4[2], m4[3]));
      mx = fmaxf(mx, __shfl_xor(mx, 16));
      mx = fmaxf(mx, __shfl_xor(mx, 32));
      float mnew = fmaxf(mold[nt], mx);
      alpha[nt] = exp2f(mold[nt] - mnew);
      mold[nt] = mnew;
      f32x4 s4 = (f32x4)0.0f;
#pragma unroll
      for (int mt = 0; mt < 8; ++mt) {
        f32x4 p;
        p[0] = exp2f(sa[mt][nt][0] - mnew);
        p[1] = exp2f(sa[mt][nt][1] - mnew);
        p[2] = exp2f(sa[mt][nt][2] - mnew);
        p[3] = exp2f(sa[mt][nt][3] - mnew);
        sa[mt][nt] = p;
        s4 += p;
      }
      float ss = (s4[0] + s4[1]) + (s4[2] + s4[3]);
      ss += __shfl_xor(ss, 16);
      ss += __shfl_xor(ss, 32);
      lsum[nt] = lsum[nt] * alpha[nt] + ss;
    }

    // rescale O by alpha (broadcast col-state -> row-state via shfl)
#pragma unroll
    for (int mo = 0; mo < 2; ++mo) {
      f32x4 av;
#pragma unroll
      for (int r = 0; r < 4; ++r) av[r] = __shfl(alpha[mo], q16 * 4 + r);
#pragma unroll
      for (int dt = 0; dt < 4; ++dt) oacc[mo][dt] *= av;
    }

    // O += P V, in two s-halves through per-wave LDS (C-layout -> A-layout)
    int G = diag ? wave + 1 : 4;  // valid 32-wide s-groups
#pragma unroll
    for (int hf = 0; hf < 2; ++hf) {
      if (hf * 2 < G) {
#pragma unroll
        for (int nt = 0; nt < 2; ++nt)
#pragma unroll
          for (int mt4 = 0; mt4 < 4; ++mt4) {
            f32x4 p = sa[hf * 4 + mt4][nt];
            uint2 w;
            w.x = pk2(p[0], p[1]);
            w.y = pk2(p[2], p[3]);
            *(uint2*)&lsPw[(nt * 16 + c16) * 72 + mt4 * 16 + q16 * 4] = w;
          }
#pragma unroll
        for (int ksh = 0; ksh < 2; ++ksh) {
          if (hf * 2 + ksh < G) {
            bf16x8 pf0 =
                *(const bf16x8*)&lsPw[c16 * 72 + ksh * 32 + q16 * 8];
            bf16x8 pf1 =
                *(const bf16x8*)&lsPw[(16 + c16) * 72 + ksh * 32 + q16 * 8];
#pragma unroll
            for (int dt = 0; dt < 4; ++dt) {
              bf16x8 vf = *(const bf16x8*)&lsV[(dt * 16 + c16) * 136 +
                                               hf * 64 + ksh * 32 + q16 * 8];
              oacc[0][dt] = mfma16(pf0, vf, oacc[0][dt]);
              oacc[1][dt] = mfma16(pf1, vf, oacc[1][dt]);
            }
          }
        }
      }
    }
  }

  // epilogue: O /= l, write (B,T,C) bf16
#pragma unroll
  for (int mo = 0; mo < 2; ++mo) {
    f32x4 lv;
#pragma unroll
    for (int r = 0; r < 4; ++r) lv[r] = __shfl(lsum[mo], q16 * 4 + r);
#pragma unroll
    for (int r = 0; r < 4; ++r) {
      int tg = q0 + wave * 32 + mo * 16 + q16 * 4 + r;
      float inv = 1.0f / lv[r];
#pragma unroll
      for (int dt = 0; dt < 4; ++dt)
        og[((size_t)b * 512 + tg) * 1024 + h * 64 + dt * 16 + c16] =
            f2b(oacc[mo][dt][r] * inv);
    }
  }
}

// ---------------- output projection GEMM ----------------
// BK=64 dual-buffer K-loop + same XOR bank swizzle as gemm_qkv.
__global__ __launch_bounds__(256) void gemm_out(
    const u16* __restrict__ A, const u16* __restrict__ W,
    const float* __restrict__ bo, float* __restrict__ out) {
  __shared__ u16 lsA[2][128 * 32];
  __shared__ u16 lsB[2][128 * 32];
  const int K = 1024;
  int tid = threadIdx.x, wave = tid >> 6, lane = tid & 63;
  int q16 = lane >> 4, c16 = lane & 15;
  int m0 = blockIdx.y * 128, n0 = blockIdx.x * 128;
  int wm = wave >> 1, wn = wave & 1;

  f32x4 acc[4][4];
#pragma unroll
  for (int i = 0; i < 4; ++i)
#pragma unroll
    for (int j = 0; j < 4; ++j) acc[i][j] = (f32x4)0.0f;

  int srow = (lane >> 2);
  int scol = ((lane & 3) ^ ((lane >> 3) & 3)) * 8;  // XOR-swizzled colgroup
  int swz = (q16 ^ ((c16 >> 1) & 3)) * 8;           // read-side colgroup

  for (int k0 = 0; k0 < K; k0 += 64) {
    __syncthreads();
#pragma unroll
    for (int half = 0; half < 2; ++half) {
#pragma unroll
      for (int cc = 0; cc < 2; ++cc) {
        int chunk = wave * 2 + cc;
        int r = chunk * 16 + srow;
        glds16(A + (size_t)(m0 + r) * K + k0 + half * 32 + scol,
               &lsA[half][chunk * 512]);
        glds16(W + (size_t)(n0 + r) * K + k0 + half * 32 + scol,
               &lsB[half][chunk * 512]);
      }
    }
    __syncthreads();
#pragma unroll
    for (int half = 0; half < 2; ++half) {
      bf16x8 af[4], bf[4];
#pragma unroll
      for (int i = 0; i < 4; ++i)
        af[i] = *(const bf16x8*)&lsA[half][(wm * 64 + i * 16 + c16) * 32 + swz];
#pragma unroll
      for (int i = 0; i < 4; ++i)
        bf[i] = *(const bf16x8*)&lsB[half][(wn * 64 + i * 16 + c16) * 32 + swz];
#pragma unroll
      for (int mt = 0; mt < 4; ++mt)
#pragma unroll
        for (int nt = 0; nt < 4; ++nt)
          acc[mt][nt] = mfma16(af[mt], bf[nt], acc[mt][nt]);
    }
  }

#pragma unroll
  for (int mt = 0; mt < 4; ++mt) {
#pragma unroll
    for (int nt = 0; nt < 4; ++nt) {
      int n = n0 + wn * 64 + nt * 16 + c16;
      float bias = bo[n];
#pragma unroll
      for (int r = 0; r < 4; ++r) {
        int m = m0 + wm * 64 + mt * 16 + q16 * 4 + r;
        out[(size_t)m * 1024 + n] = acc[mt][nt][r] + bias;
      }
    }
  }
}

extern "C" void kernel_launch(void* const* d_in, const int* in_sizes, int n_in,
                              void* d_out, int out_size, void* d_ws, size_t ws_size,
                              hipStream_t stream) {
  const float* x    = (const float*)d_in[0];
  const float* Wq   = (const float*)d_in[1];
  const float* bq   = (const float*)d_in[2];
  const float* Wk   = (const float*)d_in[3];
  const float* bk   = (const float*)d_in[4];
  const float* Wv   = (const float*)d_in[5];
  const float* bv   = (const float*)d_in[6];
  const float* Wo   = (const float*)d_in[7];
  const float* bo   = (const float*)d_in[8];
  const float* bias = (const float*)d_in[9];
  float* out = (float*)d_out;

  const size_t MB = 1u << 20;
  char* ws = (char*)d_ws;
  u16* xb    = (u16*)(ws);              // 16 MiB: x bf16 / reused as attn out
  u16* wqkv  = (u16*)(ws + 16 * MB);    // 6 MiB
  u16* wo    = (u16*)(ws + 22 * MB);    // 2 MiB
  u16* biasb = (u16*)(ws + 24 * MB);    // 8 MiB (bf16, pre-scaled by log2e)
  u16* qb    = (u16*)(ws + 32 * MB);    // 18 MiB (BH,512,72)
  u16* kb    = (u16*)(ws + 50 * MB);    // 18 MiB (BH,512,72)
  u16* vtb   = (u16*)(ws + 68 * MB);    // 17 MiB (BH,4,64,136)
  u16* ab    = xb;                      // attn output overlays xb

  cvt_all<<<16384, 256, 0, stream>>>(x, Wq, Wk, Wv, Wo, bias,
                                     xb, wqkv, wo, biasb);
  gemm_qkv<<<dim3(24, 64), 256, 0, stream>>>(xb, wqkv, bq, bk, bv, qb, kb, vtb);
  attn_kernel<<<dim3(4, 256), 256, 0, stream>>>(qb, kb, vtb, biasb, ab);
  gemm_out<<<dim3(8, 64), 256, 0, stream>>>(ab, wo, bo, out);
}